// Round 5
// baseline (124.690 us; speedup 1.0000x reference)
//
#include <hip/hip_runtime.h>

#define NPTS 128
#define FAR_DELTA 1e10f

typedef float f32x4 __attribute__((ext_vector_type(4)));

// update_dpp with old=0: disabled rows (row_mask) and OOB reads (bound_ctrl)
// yield 0 -- the add identity.
template<int CTRL, int RMASK, bool BC>
__device__ __forceinline__ float dpp0(float x) {
    return __int_as_float(__builtin_amdgcn_update_dpp(
        0, __float_as_int(x), CTRL, RMASK, 0xf, BC));
}

// Inclusive prefix sum within each 32-lane segment, pure VALU (DPP).
// Lane 31 / 63 ends with its segment's total.
__device__ __forceinline__ float scan32(float v) {
    v += dpp0<0x111, 0xf, true>(v);   // row_shr:1
    v += dpp0<0x112, 0xf, true>(v);   // row_shr:2
    v += dpp0<0x114, 0xf, true>(v);   // row_shr:4
    v += dpp0<0x118, 0xf, true>(v);   // row_shr:8
    v += dpp0<0x142, 0xa, false>(v);  // row_bcast:15 -> rows 1,3 only
    return v;
}

// One wave = 2 rays; lane owns 4 consecutive points; all loads float4.
// 1-deep software pipeline: iter k+1's loads are issued before iter k's
// compute, so the scan/exp chains overlap the next loads' flight
// (compiler emits counted vmcnt). __launch_bounds__(256,4): cap VGPR at
// 128 -> >= 16 waves/CU; in-flight bytes/CU (~160KB) >> BW*latency (~8.4KB).
__global__ __launch_bounds__(256, 4) void vr_main(
    const float* __restrict__ dv,    // [N,128] depth_values
    const float* __restrict__ dens,  // [N,128,1] density
    const float* __restrict__ feat,  // [N,128,3] feature
    float* __restrict__ out_feat,    // [N,3]
    float* __restrict__ out_depth,   // [N] raw depth (kernel 2 normalizes)
    int*   __restrict__ ws_max,      // [1] float-bits max, pre-zeroed
    int n_rays)
{
    const int lane = threadIdx.x & 63;
    const int half = lane >> 5;               // which ray of the pair
    const int li   = lane & 31;               // lane within half-wave
    const int wib  = threadIdx.x >> 6;
    const int wpb  = blockDim.x >> 6;
    const int gwave   = blockIdx.x * wpb + wib;
    const int nwaves  = gridDim.x * wpb;
    const int n_pairs = (n_rays + 1) >> 1;
    const int last_ray = n_rays - 1;

    float dmax = 0.0f;

    if (gwave < n_pairs) {
        // ---- pipeline stage 0: load first pair ----
        int pair = gwave;
        int ray_real = 2 * pair + half;
        int ray = min(ray_real, last_ray);
        size_t pbase = (size_t)ray * NPTS + 4 * li;
        f32x4 d4 = __builtin_nontemporal_load((const f32x4*)(dv   + pbase));
        f32x4 s4 = __builtin_nontemporal_load((const f32x4*)(dens + pbase));
        const float* fb = feat + (size_t)ray * (NPTS * 3) + 12 * li;
        f32x4 f0 = *(const f32x4*)(fb + 0);
        f32x4 f1 = *(const f32x4*)(fb + 4);
        f32x4 f2 = *(const f32x4*)(fb + 8);

        while (true) {
            // ---- issue next iteration's loads (wave-uniform predicate;
            //      skipped on the last iteration -> no redundant fetch) ----
            const int next = pair + nwaves;
            f32x4 nd4, ns4, nf0, nf1, nf2;
            bool have_next = (next < n_pairs);
            if (have_next) {
                const int nray = min(2 * next + half, last_ray);
                const size_t npb = (size_t)nray * NPTS + 4 * li;
                nd4 = __builtin_nontemporal_load((const f32x4*)(dv   + npb));
                ns4 = __builtin_nontemporal_load((const f32x4*)(dens + npb));
                const float* nfb = feat + (size_t)nray * (NPTS * 3) + 12 * li;
                nf0 = *(const f32x4*)(nfb + 0);
                nf1 = *(const f32x4*)(nfb + 4);
                nf2 = *(const f32x4*)(nfb + 8);
            }

            // ---- compute current pair ----
            const float dn = __shfl_down(d4.x, 1);       // depth[4(li+1)]
            const float a0 = (d4.y - d4.x) * s4.x;
            const float a1 = (d4.z - d4.y) * s4.y;
            const float a2 = (d4.w - d4.z) * s4.z;
            const float a3 = (li == 31) ? FAR_DELTA * s4.w : (dn - d4.w) * s4.w;

            // Exclusive prefix of optical depth. Lane 31's a3 carries the
            // 1e10 sentinel: never needed in any prefix; including it
            // destroys excl via catastrophic cancellation (ulp(1e10)~1024).
            const float s_scan = a0 + a1 + a2 + ((li == 31) ? 0.0f : a3);
            const float incl = scan32(s_scan);
            const float excl = incl - s_scan;            // sum over pts < 4li

            const float T0 = __expf(-excl);
            const float e0 = __expf(-a0);
            const float e1 = __expf(-a1);
            const float e2 = __expf(-a2);
            const float e3 = __expf(-a3);
            const float w0 = T0 * (1.0f - e0);
            const float T1 = T0 * e0;
            const float w1 = T1 * (1.0f - e1);
            const float T2 = T1 * e1;
            const float w2 = T2 * (1.0f - e2);
            const float T3 = T2 * e2;
            const float w3 = T3 * (1.0f - e3);

            float c0 = w0 * f0.x + w1 * f0.w + w2 * f1.z + w3 * f2.y;
            float c1 = w0 * f0.y + w1 * f1.x + w2 * f1.w + w3 * f2.z;
            float c2 = w0 * f0.z + w1 * f1.y + w2 * f2.x + w3 * f2.w;

            // Segment sums via the same DPP scan: lane 31/63 holds totals.
            c0 = scan32(c0);
            c1 = scan32(c1);
            c2 = scan32(c2);

            // depth extraction: first j in [0,50) with density > 0.1
            const bool q0 = (li <= 12) && (s4.x > 0.1f);   // j = 4li+0
            const bool q1 = (li <= 12) && (s4.y > 0.1f);   // j = 4li+1
            const bool q2 = (li <= 11) && (s4.z > 0.1f);   // j = 4li+2
            const bool q3 = (li <= 11) && (s4.w > 0.1f);   // j = 4li+3
            const unsigned long long b0 = __ballot(q0);
            const unsigned long long b1 = __ballot(q1);
            const unsigned long long b2 = __ballot(q2);
            const unsigned long long b3 = __ballot(q3);
            const int sh = 32 * half;
            const unsigned int m0 = (unsigned int)(b0 >> sh);
            const unsigned int m1 = (unsigned int)(b1 >> sh);
            const unsigned int m2 = (unsigned int)(b2 >> sh);
            const unsigned int m3 = (unsigned int)(b3 >> sh);
            int j = 1000;
            if (m0) j = min(j, 4 * (int)__builtin_ctz(m0) + 0);
            if (m1) j = min(j, 4 * (int)__builtin_ctz(m1) + 1);
            if (m2) j = min(j, 4 * (int)__builtin_ctz(m2) + 2);
            if (m3) j = min(j, 4 * (int)__builtin_ctz(m3) + 3);
            const float draw = (j < 50) ? (1.0f - (float)j * 0.02f) : 0.0f;
            dmax = fmaxf(dmax, draw);

            if (li == 31 && ray_real <= last_ray) {      // lane holding sums
                out_feat[(size_t)ray * 3 + 0] = c0;
                out_feat[(size_t)ray * 3 + 1] = c1;
                out_feat[(size_t)ray * 3 + 2] = c2;
                out_depth[ray] = draw;
            }

            if (!have_next) break;
            // ---- rotate pipeline registers ----
            pair = next;
            ray_real = 2 * pair + half;
            ray = min(ray_real, last_ray);
            d4 = nd4; s4 = ns4; f0 = nf0; f1 = nf1; f2 = nf2;
        }
    }

    // merge the two halves' maxes, then block max -> one atomic per block
    dmax = fmaxf(dmax, __shfl_xor(dmax, 32));
    __shared__ float smax[8];
    if (lane == 0) smax[wib] = dmax;
    __syncthreads();
    if (threadIdx.x == 0) {
        float m = smax[0];
        for (int i = 1; i < wpb; ++i) m = fmaxf(m, smax[i]);
        atomicMax(ws_max, __float_as_int(m));   // m >= 0: int order == float
    }
}

// Kernel 2: normalize depth by the global max (float4 vectorized).
__global__ __launch_bounds__(256) void vr_div(
    float* __restrict__ out_depth, const int* __restrict__ ws_max, int n)
{
    const int i4 = blockIdx.x * blockDim.x + threadIdx.x;
    const float inv = 1.0f / __int_as_float(*ws_max);
    const int n4 = n >> 2;
    if (i4 < n4) {
        f32x4 v = ((f32x4*)out_depth)[i4];
        v.x *= inv; v.y *= inv; v.z *= inv; v.w *= inv;
        ((f32x4*)out_depth)[i4] = v;
    }
    const int rem = n & 3;
    if (rem && i4 < rem) {
        const int t = n4 * 4 + i4;
        out_depth[t] *= inv;
    }
}

extern "C" void kernel_launch(void* const* d_in, const int* in_sizes, int n_in,
                              void* d_out, int out_size, void* d_ws, size_t ws_size,
                              hipStream_t stream) {
    const float* dv   = (const float*)d_in[0];   // [N,128]
    const float* dens = (const float*)d_in[1];   // [N,128,1]
    const float* feat = (const float*)d_in[2];   // [N,128,3]

    const int n_rays = in_sizes[0] / NPTS;

    float* out_feat  = (float*)d_out;                       // [N,3]
    float* out_depth = (float*)d_out + (size_t)n_rays * 3;  // [N,1]
    int*   ws_max    = (int*)d_ws;

    hipMemsetAsync(ws_max, 0, sizeof(int), stream);

    const int threads = 256;
    const int blocks  = 2048;   // 8192 waves = 16384 ray-slots, grid-stride
    vr_main<<<blocks, threads, 0, stream>>>(dv, dens, feat, out_feat, out_depth,
                                            ws_max, n_rays);

    const int n4 = (n_rays + 3) / 4;
    const int blocks2 = (n4 + threads - 1) / threads;
    vr_div<<<blocks2, threads, 0, stream>>>(out_depth, ws_max, n_rays);
}